// Round 1
// baseline (183.847 us; speedup 1.0000x reference)
//
#include <hip/hip_runtime.h>

#define NN 9
#define HD 16
#define HID 64

__global__ __launch_bounds__(256, 2)
void subattn_kernel(const float* __restrict__ q, const float* __restrict__ k,
                    const float* __restrict__ v, const float* __restrict__ pe,
                    const float* __restrict__ W1, const float* __restrict__ b1,
                    const float* __restrict__ W2,
                    float* __restrict__ out, int nrows)
{
    __shared__ float sW1t[HID][HD];   // [o][c] = W1[c][o]
    __shared__ float sW2[HID * HD];   // [o*16 + c]
    __shared__ float sb1[HID];

    const int tid = threadIdx.x;

    // ---- stage weights into LDS (once per block) ----
    {
        const int idx = tid * 4;          // 256 threads * 4 = 1024 = 16*64
        #pragma unroll
        for (int e = 0; e < 4; ++e) {
            int ii = idx + e;             // ii = c*64 + o
            sW1t[ii & 63][ii >> 6] = W1[ii];
        }
        ((float4*)sW2)[tid] = ((const float4*)W2)[tid];  // W2 is (64,16) row-major
        if (tid < HID) sb1[tid] = b1[tid];
    }
    __syncthreads();

    const int r = blockIdx.x * 256 + tid;
    if (r >= nrows) return;
    const int h  = r & 3;                 // head
    const int bp = r >> 2;                // (b*num_p + p)

    // ---- load q row (16 floats) ----
    float qr[16];
    {
        const float4* p4 = (const float4*)(q + (size_t)bp * 64 + h * 16);
        #pragma unroll
        for (int i = 0; i < 4; ++i) {
            float4 t = p4[i];
            qr[4*i+0] = t.x; qr[4*i+1] = t.y; qr[4*i+2] = t.z; qr[4*i+3] = t.w;
        }
    }

    float lsum[16], acc[16];
    #pragma unroll
    for (int i = 0; i < 16; ++i) { lsum[i] = 0.f; acc[i] = 0.f; }

    const size_t rowbase = (size_t)bp * (NN * 64) + h * 16;

    // ---- 3 chunks of 3 neighbors ----
    for (int jc = 0; jc < 3; ++jc) {
        float x[3][16], vp[3][16];
        #pragma unroll
        for (int jj = 0; jj < 3; ++jj) {
            const size_t base = rowbase + (size_t)(jc * 3 + jj) * 64;
            const float4* k4 = (const float4*)(k  + base);
            const float4* p4 = (const float4*)(pe + base);
            const float4* v4 = (const float4*)(v  + base);
            #pragma unroll
            for (int i = 0; i < 4; ++i) {
                float4 kk = k4[i], pp = p4[i], vv = v4[i];
                x [jj][4*i+0] = qr[4*i+0] - kk.x + pp.x;
                x [jj][4*i+1] = qr[4*i+1] - kk.y + pp.y;
                x [jj][4*i+2] = qr[4*i+2] - kk.z + pp.z;
                x [jj][4*i+3] = qr[4*i+3] - kk.w + pp.w;
                vp[jj][4*i+0] = vv.x + pp.x;
                vp[jj][4*i+1] = vv.y + pp.y;
                vp[jj][4*i+2] = vv.z + pp.z;
                vp[jj][4*i+3] = vv.w + pp.w;
            }
        }

        float s[3][16];
        #pragma unroll
        for (int jj = 0; jj < 3; ++jj)
            #pragma unroll
            for (int c = 0; c < 16; ++c) s[jj][c] = 0.f;

        // ---- MLP: 16 -> 64 (relu) -> 16, hidden-unit-outer loop ----
        #pragma unroll 4
        for (int o = 0; o < HID; ++o) {
            float w1r[16], w2r[16];
            #pragma unroll
            for (int i = 0; i < 4; ++i) {
                float4 a = ((const float4*)&sW1t[o][0])[i];
                w1r[4*i+0] = a.x; w1r[4*i+1] = a.y; w1r[4*i+2] = a.z; w1r[4*i+3] = a.w;
                float4 b = ((const float4*)(sW2 + o * 16))[i];
                w2r[4*i+0] = b.x; w2r[4*i+1] = b.y; w2r[4*i+2] = b.z; w2r[4*i+3] = b.w;
            }
            float h0 = sb1[o], h1 = h0, h2 = h0;
            #pragma unroll
            for (int c = 0; c < 16; ++c) {
                h0 = fmaf(x[0][c], w1r[c], h0);
                h1 = fmaf(x[1][c], w1r[c], h1);
                h2 = fmaf(x[2][c], w1r[c], h2);
            }
            h0 = fmaxf(h0, 0.f); h1 = fmaxf(h1, 0.f); h2 = fmaxf(h2, 0.f);
            #pragma unroll
            for (int c = 0; c < 16; ++c) {
                s[0][c] = fmaf(h0, w2r[c], s[0][c]);
                s[1][c] = fmaf(h1, w2r[c], s[1][c]);
                s[2][c] = fmaf(h2, w2r[c], s[2][c]);
            }
        }
        // NOTE: b2 is omitted: softmax over neighbors is shift-invariant in b2.

        // ---- online softmax accumulation (no max-sub: |s| <~ 8, exp safe in fp32) ----
        #pragma unroll
        for (int jj = 0; jj < 3; ++jj)
            #pragma unroll
            for (int c = 0; c < 16; ++c) {
                float e = __expf(s[jj][c]);
                lsum[c] += e;
                acc[c]  = fmaf(e, vp[jj][c], acc[c]);
            }
    }

    // ---- normalize + store ----
    float4* o4 = (float4*)(out + (size_t)bp * 64 + h * 16);
    #pragma unroll
    for (int i = 0; i < 4; ++i) {
        float4 t;
        t.x = acc[4*i+0] / lsum[4*i+0];
        t.y = acc[4*i+1] / lsum[4*i+1];
        t.z = acc[4*i+2] / lsum[4*i+2];
        t.w = acc[4*i+3] / lsum[4*i+3];
        o4[i] = t;
    }
}

extern "C" void kernel_launch(void* const* d_in, const int* in_sizes, int n_in,
                              void* d_out, int out_size, void* d_ws, size_t ws_size,
                              hipStream_t stream) {
    const float* q  = (const float*)d_in[0];
    const float* k  = (const float*)d_in[1];
    const float* v  = (const float*)d_in[2];
    const float* pe = (const float*)d_in[3];
    const float* W1 = (const float*)d_in[4];
    const float* b1 = (const float*)d_in[5];
    const float* W2 = (const float*)d_in[6];
    // d_in[7] = b2: provably cancels in softmax over neighbors.
    float* out = (float*)d_out;

    const int nrows = in_sizes[0] / 16;   // (bs*num_p) * 4 heads
    const int grid  = (nrows + 255) / 256;
    subattn_kernel<<<grid, 256, 0, stream>>>(q, k, v, pe, W1, b1, W2, out, nrows);
}